// Round 1
// baseline (792.849 us; speedup 1.0000x reference)
//
#include <hip/hip_runtime.h>

typedef unsigned short u16;
typedef _Float16 f16;
typedef __attribute__((ext_vector_type(8))) f16 f16x8;
typedef __attribute__((ext_vector_type(4))) float fx4;
typedef __attribute__((ext_vector_type(8))) u16 u16x8;
typedef __attribute__((ext_vector_type(4))) u16 u16x4;

#define SZE 8388608u  // 16384*512 elements per [B*L, D] matrix

__device__ __forceinline__ u16 f2h_bits(float x) {
  union { f16 h; u16 u; } v; v.h = (f16)x; return v.u;
}

// async global->LDS, 16B per lane. LDS dest is wave-uniform base + lane*16,
// so LDS layout must be contiguous in lane order (no padding) — we instead
// swizzle the CHUNK ordering so MFMA fragment reads are 2-way-max conflicts.
__device__ __forceinline__ void gl2lds16(const void* g, void* l) {
  __builtin_amdgcn_global_load_lds(
      (const __attribute__((address_space(1))) unsigned int*)g,
      (__attribute__((address_space(3))) unsigned int*)l, 16, 0, 0);
}

// ---------------- kernel 1: fp32 -> fp16 convert of both inputs ------------
__global__ __launch_bounds__(256) void convert_x(const float* __restrict__ x0,
                                                 const float* __restrict__ x1,
                                                 u16* __restrict__ xh) {
  size_t i = ((size_t)blockIdx.x * 256 + threadIdx.x) * 8;
  const float* src = (i < SZE) ? (x0 + i) : (x1 + (i - SZE));
  float4 a = *(const float4*)(src);
  float4 b = *(const float4*)(src + 4);
  u16x8 o;
  o[0] = f2h_bits(a.x); o[1] = f2h_bits(a.y);
  o[2] = f2h_bits(a.z); o[3] = f2h_bits(a.w);
  o[4] = f2h_bits(b.x); o[5] = f2h_bits(b.y);
  o[6] = f2h_bits(b.z); o[7] = f2h_bits(b.w);
  *(u16x8*)(xh + i) = o;
}

// ---------------- kernel 2: W [K][N] fp32 -> Wt [N][K] fp16 ----------------
__global__ __launch_bounds__(256) void wtrans(
    const float* __restrict__ w0, const float* __restrict__ w1,
    const float* __restrict__ w2, const float* __restrict__ w3,
    const float* __restrict__ w4, const float* __restrict__ w5,
    u16* __restrict__ wt) {
  __shared__ float tile[32][33];
  const int z = blockIdx.z;
  const float* W = z == 0 ? w0 : z == 1 ? w1 : z == 2 ? w2
                 : z == 3 ? w3 : z == 4 ? w4 : w5;
  u16* WT = wt + (size_t)z * 262144u;
  const int k0 = blockIdx.x * 32, n0 = blockIdx.y * 32;
  const int tx = threadIdx.x, ty = threadIdx.y;  // 32 x 8
  for (int j = 0; j < 32; j += 8)
    tile[ty + j][tx] = W[(size_t)(k0 + ty + j) * 512 + n0 + tx];
  __syncthreads();
  for (int j = 0; j < 32; j += 8)
    WT[(size_t)(n0 + ty + j) * 512 + k0 + tx] = f2h_bits(tile[tx][ty + j]);
}

// ---------------- kernel 3: six projections, C = X*W + b -------------------
// 128x128 tile, BK=32, 256 thr (4 waves, each 64x64 via 4x4 16x16x32 MFMA).
// LDS chunk layout [q][row] (chunk = 8 halves along k): frag ds_read_b128 is
// 2-way bank aliased only (free). proj%3==2 (V) stores transposed [B][D][L].
__global__ __launch_bounds__(256, 2) void proj_gemm(
    const u16* __restrict__ xh, const u16* __restrict__ wt,
    u16* __restrict__ qkv,
    const float* __restrict__ b0, const float* __restrict__ b1,
    const float* __restrict__ b2, const float* __restrict__ b3,
    const float* __restrict__ b4, const float* __restrict__ b5) {
  const int proj = blockIdx.z;
  const u16* X = xh + (proj < 3 ? 0u : SZE);
  const u16* W = wt + (size_t)proj * 262144u;
  u16* out = qkv + (size_t)proj * SZE;
  const float* bias = proj == 0 ? b0 : proj == 1 ? b1 : proj == 2 ? b2
                    : proj == 3 ? b3 : proj == 4 ? b4 : b5;
  const int m0 = blockIdx.x * 128, n0 = blockIdx.y * 128;
  const int t = threadIdx.x, lane = t & 63, w = t >> 6;
  const int wr = w >> 1, wc = w & 1, ml = lane & 15, q = lane >> 4;
  __shared__ u16 sA[4096], sB[4096];
  fx4 acc[4][4] = {};
  for (int k0 = 0; k0 < 512; k0 += 32) {
    for (int r = 0; r < 2; ++r) {
      int c = r * 256 + t;
      int cq = c >> 7, cm = c & 127;
      gl2lds16(X + (size_t)(m0 + cm) * 512 + (k0 + cq * 8), sA + c * 8);
      gl2lds16(W + (size_t)(n0 + cm) * 512 + (k0 + cq * 8), sB + c * 8);
    }
    __syncthreads();
    f16x8 af[4], bf[4];
    for (int i = 0; i < 4; ++i) {
      af[i] = *(const f16x8*)(sA + (q * 128 + wr * 64 + i * 16 + ml) * 8);
      bf[i] = *(const f16x8*)(sB + (q * 128 + wc * 64 + i * 16 + ml) * 8);
    }
    for (int i = 0; i < 4; ++i)
      for (int j = 0; j < 4; ++j)
        acc[i][j] = __builtin_amdgcn_mfma_f32_16x16x32_f16(af[i], bf[j],
                                                           acc[i][j], 0, 0, 0);
    __syncthreads();
  }
  const bool vtrans = (proj % 3) == 2;
  for (int j = 0; j < 4; ++j) {
    const int n = n0 + wc * 64 + j * 16 + ml;
    const float bv = bias[n];
    for (int i = 0; i < 4; ++i) {
      const int mb = m0 + wr * 64 + i * 16 + q * 4;
      if (!vtrans) {
        for (int r = 0; r < 4; ++r)
          out[(size_t)(mb + r) * 512 + n] = f2h_bits(acc[i][j][r] + bv);
      } else {
        const int bb = mb >> 11, l = mb & 2047;
        u16x4 pk;
        for (int r = 0; r < 4; ++r) pk[r] = f2h_bits(acc[i][j][r] + bv);
        *(u16x4*)(out + ((size_t)bb * 512 + n) * 2048 + l) = pk;
      }
    }
  }
}

// ---------------- kernel 4: flash cross-attention --------------------------
// BM=64 queries/block, BN=32 keys/iter, 512 thr (8 waves).
// wave w: S-tile (mi=w&3, ni=w>>2) for QK^T; d-slice [w*64,w*64+64) for PV.
// Q frags in registers (64 VGPR). K staged via global_load_lds, chunk layout
// [ks][q][s]. V frags direct from global (quad covers a full 64B line).
// P through LDS in A-operand chunk layout [kq][row].
__global__ __launch_bounds__(512, 2) void attn_kernel(const u16* __restrict__ qkv,
                                                      float* __restrict__ out) {
  const int t = threadIdx.x, lane = t & 63, w = t >> 6;
  const int ml = lane & 15, q = lane >> 4;
  const int mi = w & 3, ni = w >> 2;  // S-tile coords (ni in 0..1)
  const int qt = blockIdx.x;
  const int b = blockIdx.y >> 1, tt = blockIdx.y & 1;
  // tt=0: softmax(Qr Kh^T) Vr -> out0 ; tt=1: softmax(Qh Kr^T) Vh -> out1
  const u16* Q  = qkv + (tt ? (size_t)3 * SZE : (size_t)0);
  const u16* K  = qkv + (tt ? (size_t)1 * SZE : (size_t)4 * SZE);
  const u16* Vt = qkv + (tt ? (size_t)5 * SZE : (size_t)2 * SZE);
  float* O = out + (tt ? (size_t)SZE : (size_t)0) +
             ((size_t)b * 2048 + qt * 64) * 512;
  const u16* Qb = Q + ((size_t)b * 2048 + qt * 64) * 512;
  const u16* Kb = K + (size_t)b * 2048 * 512;
  const u16* Vb = Vt + (size_t)b * 512 * 2048;  // [D][L]

  __shared__ u16 sK[16384];  // 32KB, 2048 chunks [db(16)][cq(4)][s(32)]
  __shared__ u16 sP[2048];   // 4KB, 256 chunks [kq(4)][row(64)]
  __shared__ float rmax2[2][64], rsum2[2][64], alpha_s[64], mrun[64], lrun[64];

  if (t < 64) { mrun[t] = -3.0e38f; lrun[t] = 0.0f; }

  f16x8 qf[16];  // A-op frags: Q[mi*16+ml][ks*32 + q*8 + j]
  for (int ks = 0; ks < 16; ++ks)
    qf[ks] = *(const f16x8*)(Qb + (size_t)(mi * 16 + ml) * 512 + ks * 32 + q * 8);

  const u16* vb[4];
  for (int nj = 0; nj < 4; ++nj)
    vb[nj] = Vb + (size_t)(w * 64 + nj * 16 + ml) * 2048 + q * 8;

  fx4 acc[4][4] = {};  // [m-tile][d-tile], rows=q*4+reg, col=ml

  for (int it = 0; it < 64; ++it) {
    const int k0 = it * 32;
    f16x8 vf[4];  // prefetch V B-op frags early (consumed in PV)
    for (int nj = 0; nj < 4; ++nj) vf[nj] = *(const f16x8*)(vb[nj] + k0);
    for (int r = 0; r < 4; ++r) {
      int c = r * 512 + t;
      int db = c >> 7, cq = (c >> 5) & 3, s = c & 31;
      gl2lds16(Kb + (size_t)(k0 + s) * 512 + db * 32 + cq * 8, sK + c * 8);
    }
    __syncthreads();
    // ---- QK^T for this wave's 16x16 S tile (fp32 acc) ----
    fx4 sa = {0.f, 0.f, 0.f, 0.f};
    for (int ks = 0; ks < 16; ++ks) {
      f16x8 kf = *(const f16x8*)(sK + (ks * 128 + q * 32 + ni * 16 + ml) * 8);
      sa = __builtin_amdgcn_mfma_f32_16x16x32_f16(qf[ks], kf, sa, 0, 0, 0);
    }
    // row max over the tile's 16 cols (lanes of same quad)
    fx4 mx = sa;
    for (int d = 1; d < 16; d <<= 1) {
      mx[0] = fmaxf(mx[0], __shfl_xor(mx[0], d));
      mx[1] = fmaxf(mx[1], __shfl_xor(mx[1], d));
      mx[2] = fmaxf(mx[2], __shfl_xor(mx[2], d));
      mx[3] = fmaxf(mx[3], __shfl_xor(mx[3], d));
    }
    if (ml == 0)
      for (int r = 0; r < 4; ++r) rmax2[ni][mi * 16 + q * 4 + r] = mx[r];
    __syncthreads();
    // ---- online-softmax state update (one thread per query row) ----
    if (t < 64) {
      float tm = fmaxf(rmax2[0][t], rmax2[1][t]);
      float mo = mrun[t];
      float mn2 = fmaxf(mo, tm);
      mrun[t] = mn2;
      alpha_s[t] = __expf(mo - mn2);
    }
    __syncthreads();
    // ---- P = exp(S - m_new), row sums, write P to LDS (A-layout chunks) ----
    fx4 p;
    for (int r = 0; r < 4; ++r)
      p[r] = __expf(sa[r] - mrun[mi * 16 + q * 4 + r]);
    fx4 sm = p;
    for (int d = 1; d < 16; d <<= 1) {
      sm[0] += __shfl_xor(sm[0], d);
      sm[1] += __shfl_xor(sm[1], d);
      sm[2] += __shfl_xor(sm[2], d);
      sm[3] += __shfl_xor(sm[3], d);
    }
    if (ml == 0)
      for (int r = 0; r < 4; ++r) rsum2[ni][mi * 16 + q * 4 + r] = sm[r];
    {
      const int cc = ni * 16 + ml;          // P column (key index in tile)
      const int base = (cc >> 3) * 64, cl = cc & 7;
      for (int r = 0; r < 4; ++r)
        sP[(base + mi * 16 + q * 4 + r) * 8 + cl] = f2h_bits(p[r]);
    }
    __syncthreads();
    // ---- rescale acc by alpha, accumulate P*V; update l ----
    if (t < 64) lrun[t] = alpha_s[t] * lrun[t] + rsum2[0][t] + rsum2[1][t];
    for (int mt = 0; mt < 4; ++mt) {
      const float al0 = alpha_s[mt * 16 + q * 4 + 0];
      const float al1 = alpha_s[mt * 16 + q * 4 + 1];
      const float al2 = alpha_s[mt * 16 + q * 4 + 2];
      const float al3 = alpha_s[mt * 16 + q * 4 + 3];
      f16x8 pf = *(const f16x8*)(sP + (q * 64 + mt * 16 + ml) * 8);
      for (int nj = 0; nj < 4; ++nj) {
        acc[mt][nj][0] *= al0; acc[mt][nj][1] *= al1;
        acc[mt][nj][2] *= al2; acc[mt][nj][3] *= al3;
        acc[mt][nj] = __builtin_amdgcn_mfma_f32_16x16x32_f16(pf, vf[nj],
                                                             acc[mt][nj], 0, 0, 0);
      }
    }
    __syncthreads();
  }
  // ---- epilogue: O = acc / l ----
  for (int mt = 0; mt < 4; ++mt) {
    const float i0 = 1.0f / lrun[mt * 16 + q * 4 + 0];
    const float i1 = 1.0f / lrun[mt * 16 + q * 4 + 1];
    const float i2 = 1.0f / lrun[mt * 16 + q * 4 + 2];
    const float i3 = 1.0f / lrun[mt * 16 + q * 4 + 3];
    for (int nj = 0; nj < 4; ++nj) {
      const int col = w * 64 + nj * 16 + ml;
      float* Op = O + (size_t)(mt * 16 + q * 4) * 512 + col;
      Op[0]    = acc[mt][nj][0] * i0;
      Op[512]  = acc[mt][nj][1] * i1;
      Op[1024] = acc[mt][nj][2] * i2;
      Op[1536] = acc[mt][nj][3] * i3;
    }
  }
}

extern "C" void kernel_launch(void* const* d_in, const int* in_sizes, int n_in,
                              void* d_out, int out_size, void* d_ws, size_t ws_size,
                              hipStream_t stream) {
  // ws layout (u16 elems): [xh: 2*SZE][wt: 6*512*512][qkv: 6*SZE]
  //   qkv order: 0=Qr 1=Kr 2=Vr^T 3=Qh 4=Kh 5=Vh^T   (~137.4 MB total)
  u16* ws = (u16*)d_ws;
  u16* xh = ws;
  u16* wt = ws + 16777216u;            // 2*SZE
  u16* qkv = ws + 18350080u;           // 2*SZE + 6*262144

  convert_x<<<8192, 256, 0, stream>>>((const float*)d_in[0],
                                      (const float*)d_in[1], xh);
  wtrans<<<dim3(16, 16, 6), dim3(32, 8), 0, stream>>>(
      (const float*)d_in[2], (const float*)d_in[4], (const float*)d_in[6],
      (const float*)d_in[8], (const float*)d_in[10], (const float*)d_in[12], wt);
  proj_gemm<<<dim3(128, 4, 6), 256, 0, stream>>>(
      xh, wt, qkv,
      (const float*)d_in[3], (const float*)d_in[5], (const float*)d_in[7],
      (const float*)d_in[9], (const float*)d_in[11], (const float*)d_in[13]);
  attn_kernel<<<dim3(32, 16), 512, 0, stream>>>(qkv, (float*)d_out);
}

// Round 2
// 586.860 us; speedup vs baseline: 1.3510x; 1.3510x over previous
//
#include <hip/hip_runtime.h>

typedef unsigned short u16;
typedef _Float16 f16;
typedef __attribute__((ext_vector_type(8))) f16 f16x8;
typedef __attribute__((ext_vector_type(4))) float fx4;
typedef __attribute__((ext_vector_type(8))) u16 u16x8;
typedef __attribute__((ext_vector_type(4))) u16 u16x4;

#define SZE 8388608u  // 16384*512 elements per [B*L, D] matrix

__device__ __forceinline__ u16 f2h_bits(float x) {
  union { f16 h; u16 u; } v; v.h = (f16)x; return v.u;
}

// async global->LDS, 16B per lane; dest is wave-uniform base + lane*16.
__device__ __forceinline__ void gl2lds16(const void* g, void* l) {
  __builtin_amdgcn_global_load_lds(
      (const __attribute__((address_space(1))) unsigned int*)g,
      (__attribute__((address_space(3))) unsigned int*)l, 16, 0, 0);
}

// ---------------- kernel 1: fp32 -> fp16 convert of both inputs ------------
__global__ __launch_bounds__(256) void convert_x(const float* __restrict__ x0,
                                                 const float* __restrict__ x1,
                                                 u16* __restrict__ xh) {
  size_t i = ((size_t)blockIdx.x * 256 + threadIdx.x) * 8;
  const float* src = (i < SZE) ? (x0 + i) : (x1 + (i - SZE));
  float4 a = *(const float4*)(src);
  float4 b = *(const float4*)(src + 4);
  u16x8 o;
  o[0] = f2h_bits(a.x); o[1] = f2h_bits(a.y);
  o[2] = f2h_bits(a.z); o[3] = f2h_bits(a.w);
  o[4] = f2h_bits(b.x); o[5] = f2h_bits(b.y);
  o[6] = f2h_bits(b.z); o[7] = f2h_bits(b.w);
  *(u16x8*)(xh + i) = o;
}

// ---------------- kernel 2: W [K][N] fp32 -> Wt [N][K] fp16 ----------------
__global__ __launch_bounds__(256) void wtrans(
    const float* __restrict__ w0, const float* __restrict__ w1,
    const float* __restrict__ w2, const float* __restrict__ w3,
    const float* __restrict__ w4, const float* __restrict__ w5,
    u16* __restrict__ wt) {
  __shared__ float tile[32][33];
  const int z = blockIdx.z;
  const float* W = z == 0 ? w0 : z == 1 ? w1 : z == 2 ? w2
                 : z == 3 ? w3 : z == 4 ? w4 : w5;
  u16* WT = wt + (size_t)z * 262144u;
  const int k0 = blockIdx.x * 32, n0 = blockIdx.y * 32;
  const int tx = threadIdx.x, ty = threadIdx.y;  // 32 x 8
  for (int j = 0; j < 32; j += 8)
    tile[ty + j][tx] = W[(size_t)(k0 + ty + j) * 512 + n0 + tx];
  __syncthreads();
  for (int j = 0; j < 32; j += 8)
    WT[(size_t)(n0 + ty + j) * 512 + k0 + tx] = f2h_bits(tile[tx][ty + j]);
}

// ---------------- kernel 3: six projections, C = X*W + b -------------------
__global__ __launch_bounds__(256, 2) void proj_gemm(
    const u16* __restrict__ xh, const u16* __restrict__ wt,
    u16* __restrict__ qkv,
    const float* __restrict__ b0, const float* __restrict__ b1,
    const float* __restrict__ b2, const float* __restrict__ b3,
    const float* __restrict__ b4, const float* __restrict__ b5) {
  const int proj = blockIdx.z;
  const u16* X = xh + (proj < 3 ? 0u : SZE);
  const u16* W = wt + (size_t)proj * 262144u;
  u16* out = qkv + (size_t)proj * SZE;
  const float* bias = proj == 0 ? b0 : proj == 1 ? b1 : proj == 2 ? b2
                    : proj == 3 ? b3 : proj == 4 ? b4 : b5;
  const int m0 = blockIdx.x * 128, n0 = blockIdx.y * 128;
  const int t = threadIdx.x, lane = t & 63, w = t >> 6;
  const int wr = w >> 1, wc = w & 1, ml = lane & 15, q = lane >> 4;
  __shared__ u16 sA[4096], sB[4096];
  fx4 acc[4][4] = {};
  for (int k0 = 0; k0 < 512; k0 += 32) {
    for (int r = 0; r < 2; ++r) {
      int c = r * 256 + t;
      int cq = c >> 7, cm = c & 127;
      gl2lds16(X + (size_t)(m0 + cm) * 512 + (k0 + cq * 8), sA + c * 8);
      gl2lds16(W + (size_t)(n0 + cm) * 512 + (k0 + cq * 8), sB + c * 8);
    }
    __syncthreads();
    f16x8 af[4], bf[4];
    for (int i = 0; i < 4; ++i) {
      af[i] = *(const f16x8*)(sA + (q * 128 + wr * 64 + i * 16 + ml) * 8);
      bf[i] = *(const f16x8*)(sB + (q * 128 + wc * 64 + i * 16 + ml) * 8);
    }
    for (int i = 0; i < 4; ++i)
      for (int j = 0; j < 4; ++j)
        acc[i][j] = __builtin_amdgcn_mfma_f32_16x16x32_f16(af[i], bf[j],
                                                           acc[i][j], 0, 0, 0);
    __syncthreads();
  }
  const bool vtrans = (proj % 3) == 2;
  for (int j = 0; j < 4; ++j) {
    const int n = n0 + wc * 64 + j * 16 + ml;
    const float bv = bias[n];
    for (int i = 0; i < 4; ++i) {
      const int mb = m0 + wr * 64 + i * 16 + q * 4;
      if (!vtrans) {
        for (int r = 0; r < 4; ++r)
          out[(size_t)(mb + r) * 512 + n] = f2h_bits(acc[i][j][r] + bv);
      } else {
        const int bb = mb >> 11, l = mb & 2047;
        u16x4 pk;
        for (int r = 0; r < 4; ++r) pk[r] = f2h_bits(acc[i][j][r] + bv);
        *(u16x4*)(out + ((size_t)bb * 512 + n) * 2048 + l) = pk;
      }
    }
  }
}

// ---------------- kernel 4: flash cross-attention (wave-autonomous) --------
// Block = 8 waves = 128 queries; each wave owns 16 query rows end-to-end:
// softmax state (m, l, alpha) in registers (rows q*4+r match C-layout of both
// QK^T and PV accumulators) -> NO cross-wave softmax traffic, 2 barriers/iter.
// K (32x512) and V^T (512x32) staged in LDS per iter, shared by all 8 waves.
// P transposed C->A layout via per-wave-private padded LDS slab (no barrier).
// XCD swizzle: all 16 blocks of a (b,tt) group land on one XCD -> K/V stream
// stays L2-resident.
__global__ __launch_bounds__(512, 2) void attn_kernel(const u16* __restrict__ qkv,
                                                      float* __restrict__ out) {
  const int t = threadIdx.x, lane = t & 63, w = t >> 6;
  const int ml = lane & 15, q = lane >> 4;
  // block swizzle: xcd = n%8 gets (b,tt) groups {2*xcd, 2*xcd+1}
  const int n = blockIdx.x;
  const int xcd = n & 7, slot = n >> 3;
  const int g = xcd * 2 + (slot >> 4);
  const int qt = slot & 15;
  const int b = g >> 1, tt = g & 1;

  const u16* Q  = qkv + (tt ? (size_t)3 * SZE : (size_t)0);
  const u16* K  = qkv + (tt ? (size_t)1 * SZE : (size_t)4 * SZE);
  const u16* Vt = qkv + (tt ? (size_t)5 * SZE : (size_t)2 * SZE);
  float* O = out + (tt ? (size_t)SZE : (size_t)0) +
             ((size_t)b * 2048 + qt * 128) * 512;
  const u16* Qb = Q + ((size_t)b * 2048 + qt * 128) * 512;
  const u16* Kb = K + (size_t)b * 2048 * 512;
  const u16* Vb = Vt + (size_t)b * 512 * 2048;  // [D][L]

  __shared__ u16 sK[16384];      // 32KB: chunk p = dchunk*32 + key (dchunk=d/8)
  __shared__ u16 sV[16384];      // 32KB: chunk p = kc*512 + d (kc=key/8)
  __shared__ u16 sP[8 * 640];    // per-wave 16 rows x 40 halves (pad 8)

  // Q A-frags for this wave's 16 rows (64 VGPR, held all 64 iters)
  f16x8 qf[16];
  {
    const u16* qrow = Qb + (size_t)(w * 16 + ml) * 512 + q * 8;
#pragma unroll
    for (int ks = 0; ks < 16; ++ks)
      qf[ks] = *(const f16x8*)(qrow + ks * 32);
  }

  fx4 acc[32] = {};  // O tile nj: rows q*4+r, col nj*16+ml  (128 VGPR)
  fx4 mrun = {-3.0e38f, -3.0e38f, -3.0e38f, -3.0e38f};
  fx4 lrun = {0.f, 0.f, 0.f, 0.f};
  u16* wp = sP + w * 640;

  for (int it = 0; it < 64; ++it) {
    const int k0 = it * 32;
    // ---- stage K tile (32 keys x 512 d) + V^T tile (512 d x 32 keys) ----
#pragma unroll
    for (int r = 0; r < 4; ++r) {
      int p = r * 512 + t;
      gl2lds16(Kb + (size_t)(k0 + (p & 31)) * 512 + (p >> 5) * 8, sK + p * 8);
    }
#pragma unroll
    for (int r = 0; r < 4; ++r) {
      int p = r * 512 + t;
      gl2lds16(Vb + (size_t)(p & 511) * 2048 + k0 + (p >> 9) * 8, sV + p * 8);
    }
    __syncthreads();
    // ---- QK^T: S[16 rows][32 keys] = 2 tiles ----
    fx4 s0 = {0.f, 0.f, 0.f, 0.f}, s1 = {0.f, 0.f, 0.f, 0.f};
#pragma unroll
    for (int ks = 0; ks < 16; ++ks) {
      f16x8 kf0 = *(const f16x8*)(sK + ((ks * 4 + q) * 32 + ml) * 8);
      f16x8 kf1 = *(const f16x8*)(sK + ((ks * 4 + q) * 32 + 16 + ml) * 8);
      s0 = __builtin_amdgcn_mfma_f32_16x16x32_f16(qf[ks], kf0, s0, 0, 0, 0);
      s1 = __builtin_amdgcn_mfma_f32_16x16x32_f16(qf[ks], kf1, s1, 0, 0, 0);
    }
    // ---- in-wave online softmax (rows live in quads; reduce over 16 lanes)
    fx4 mx, alpha, p0, p1, sm;
#pragma unroll
    for (int r = 0; r < 4; ++r) mx[r] = fmaxf(s0[r], s1[r]);
#pragma unroll
    for (int d = 1; d < 16; d <<= 1) {
      mx[0] = fmaxf(mx[0], __shfl_xor(mx[0], d));
      mx[1] = fmaxf(mx[1], __shfl_xor(mx[1], d));
      mx[2] = fmaxf(mx[2], __shfl_xor(mx[2], d));
      mx[3] = fmaxf(mx[3], __shfl_xor(mx[3], d));
    }
    bool need = false;
#pragma unroll
    for (int r = 0; r < 4; ++r) {
      float mn = fmaxf(mrun[r], mx[r]);
      alpha[r] = __expf(mrun[r] - mn);
      mrun[r] = mn;
      p0[r] = __expf(s0[r] - mn);
      p1[r] = __expf(s1[r] - mn);
      sm[r] = p0[r] + p1[r];
      need |= (alpha[r] != 1.0f);
    }
#pragma unroll
    for (int d = 1; d < 16; d <<= 1) {
      sm[0] += __shfl_xor(sm[0], d);
      sm[1] += __shfl_xor(sm[1], d);
      sm[2] += __shfl_xor(sm[2], d);
      sm[3] += __shfl_xor(sm[3], d);
    }
    // ---- P -> per-wave LDS slab in A-operand layout [row][key], stride 40
#pragma unroll
    for (int r = 0; r < 4; ++r) {
      wp[(q * 4 + r) * 40 + ml] = f2h_bits(p0[r]);
      wp[(q * 4 + r) * 40 + 16 + ml] = f2h_bits(p1[r]);
    }
#pragma unroll
    for (int r = 0; r < 4; ++r) lrun[r] = alpha[r] * lrun[r] + sm[r];
    // ---- rescale acc (skip when no row saw a new max this iter) ----
    if (__any(need)) {
#pragma unroll
      for (int nj = 0; nj < 32; ++nj) {
        acc[nj][0] *= alpha[0]; acc[nj][1] *= alpha[1];
        acc[nj][2] *= alpha[2]; acc[nj][3] *= alpha[3];
      }
    }
    f16x8 pf = *(const f16x8*)(wp + ml * 40 + q * 8);
    // ---- PV: acc[nj] += P[16x32] * V[32x(nj-th 16 of d)] ----
#pragma unroll
    for (int nj = 0; nj < 32; ++nj) {
      f16x8 vf = *(const f16x8*)(sV + (q * 512 + nj * 16 + ml) * 8);
      acc[nj] = __builtin_amdgcn_mfma_f32_16x16x32_f16(pf, vf, acc[nj], 0, 0, 0);
    }
    __syncthreads();
  }
  // ---- epilogue: O = acc / l ----
  fx4 linv;
#pragma unroll
  for (int r = 0; r < 4; ++r) linv[r] = 1.0f / lrun[r];
  float* Ob = O + (size_t)(w * 16 + q * 4) * 512 + ml;
#pragma unroll
  for (int nj = 0; nj < 32; ++nj) {
#pragma unroll
    for (int r = 0; r < 4; ++r)
      Ob[(size_t)r * 512 + nj * 16] = acc[nj][r] * linv[r];
  }
}

extern "C" void kernel_launch(void* const* d_in, const int* in_sizes, int n_in,
                              void* d_out, int out_size, void* d_ws, size_t ws_size,
                              hipStream_t stream) {
  // ws layout (u16 elems): [xh: 2*SZE][wt: 6*512*512][qkv: 6*SZE]
  //   qkv order: 0=Qr 1=Kr 2=Vr^T 3=Qh 4=Kh 5=Vh^T
  u16* ws = (u16*)d_ws;
  u16* xh = ws;
  u16* wt = ws + 16777216u;            // 2*SZE
  u16* qkv = ws + 18350080u;           // 2*SZE + 6*262144

  convert_x<<<8192, 256, 0, stream>>>((const float*)d_in[0],
                                      (const float*)d_in[1], xh);
  wtrans<<<dim3(16, 16, 6), dim3(32, 8), 0, stream>>>(
      (const float*)d_in[2], (const float*)d_in[4], (const float*)d_in[6],
      (const float*)d_in[8], (const float*)d_in[10], (const float*)d_in[12], wt);
  proj_gemm<<<dim3(128, 4, 6), 256, 0, stream>>>(
      xh, wt, qkv,
      (const float*)d_in[3], (const float*)d_in[5], (const float*)d_in[7],
      (const float*)d_in[9], (const float*)d_in[11], (const float*)d_in[13]);
  attn_kernel<<<256, 512, 0, stream>>>(qkv, (float*)d_out);
}